// Round 17
// baseline (200.173 us; speedup 1.0000x reference)
//
#include <hip/hip_runtime.h>
#include <hip/hip_fp16.h>
#include <math.h>

#define BB 16
#define SS 256
#define FF 512
#define EE 128
#define HH 64
#define GG 192  // 3H
#define LL 8
#define TT 16   // scan tile count (SS/16)

typedef __fp16 f16x2 __attribute__((ext_vector_type(2)));

__device__ __forceinline__ float sigmoid_f(float x) {
    return 1.0f / (1.0f + __expf(-x));
}
__device__ __forceinline__ float tanh_f(float x) {
    return 1.0f - 2.0f / (1.0f + __expf(2.0f * x));
}

// ---------------------------------------------------------------------------
// Generic C[m,n] = sum_k A[m,k] * Bm[n,k] + bias[n]
// ---------------------------------------------------------------------------
__device__ __forceinline__ void gemm_bt_body(
    const float* __restrict__ A, const float* __restrict__ Bm,
    const float* __restrict__ bias, float* __restrict__ C,
    int N, int K)
{
    __shared__ float As[32][68];
    __shared__ float Bs[64][68];
    const int t = threadIdx.x;
    const int row0 = blockIdx.x * 32;
    const int col0 = blockIdx.y * 64;
    const int tr = t & 7;
    const int tc = t >> 3;
    float acc[4][2] = {{0.f,0.f},{0.f,0.f},{0.f,0.f},{0.f,0.f}};

    for (int k0 = 0; k0 < K; k0 += 64) {
        {
            int r = t >> 3;
            int q = t & 7;
            const float* src = &A[(size_t)(row0 + r) * K + k0];
            #pragma unroll
            for (int it = 0; it < 2; ++it) {
                int kk = (q + it * 8) * 4;
                *(float4*)&As[r][kk] = *(const float4*)&src[kk];
            }
        }
        {
            int r = t >> 2;
            int q = t & 3;
            int n = col0 + r;
            #pragma unroll
            for (int it = 0; it < 4; ++it) {
                int kk = (q + it * 4) * 4;
                float4 v = {0.f, 0.f, 0.f, 0.f};
                if (n < N) v = *(const float4*)&Bm[(size_t)n * K + k0 + kk];
                *(float4*)&Bs[r][kk] = v;
            }
        }
        __syncthreads();
        #pragma unroll
        for (int k = 0; k < 64; k += 4) {
            float4 av[4], bv[2];
            #pragma unroll
            for (int i = 0; i < 4; ++i) av[i] = *(const float4*)&As[tr + 8*i][k];
            #pragma unroll
            for (int j = 0; j < 2; ++j) bv[j] = *(const float4*)&Bs[tc + 32*j][k];
            #pragma unroll
            for (int i = 0; i < 4; ++i)
                #pragma unroll
                for (int j = 0; j < 2; ++j)
                    acc[i][j] += av[i].x*bv[j].x + av[i].y*bv[j].y
                               + av[i].z*bv[j].z + av[i].w*bv[j].w;
        }
        __syncthreads();
    }

    #pragma unroll
    for (int i = 0; i < 4; ++i) {
        int r = row0 + tr + 8*i;
        #pragma unroll
        for (int j = 0; j < 2; ++j) {
            int c = col0 + tc + 32*j;
            if (c < N) C[(size_t)r * N + c] = acc[i][j] + bias[c];
        }
    }
}

__global__ __launch_bounds__(256) void gemm_bt(
    const float* __restrict__ A, const float* __restrict__ Bm,
    const float* __restrict__ bias, float* __restrict__ C,
    int N, int K)
{
    gemm_bt_body(A, Bm, bias, C, N, K);
}

__global__ __launch_bounds__(256) void gemm_bt_dual(
    const float* __restrict__ A,
    const float* __restrict__ B0, const float* __restrict__ bias0, float* __restrict__ C0,
    const float* __restrict__ B1, const float* __restrict__ bias1, float* __restrict__ C1,
    int N, int K)
{
    const float* Bm   = blockIdx.z ? B1    : B0;
    const float* bias = blockIdx.z ? bias1 : bias0;
    float*       C    = blockIdx.z ? C1    : C0;
    gemm_bt_body(A, Bm, bias, C, N, K);
}

// ---------------------------------------------------------------------------
// Prep: pack Whh (192x64 fp32) into f16 pairs (192x32 u32), both GRUs.
// ---------------------------------------------------------------------------
__global__ __launch_bounds__(256) void cvt_w16_kernel(
    const float* __restrict__ Whh_a, const float* __restrict__ Whh_b,
    unsigned* __restrict__ wa16, unsigned* __restrict__ wb16)
{
    int i = blockIdx.x * 256 + threadIdx.x;   // 0..6143
    if (i < GG * HH / 2) {
        float2 a = ((const float2*)Whh_a)[i];
        float2 b = ((const float2*)Whh_b)[i];
        f16x2 pa = __builtin_amdgcn_cvt_pkrtz(a.x, a.y);
        f16x2 pb = __builtin_amdgcn_cvt_pkrtz(b.x, b.y);
        wa16[i] = __builtin_bit_cast(unsigned, pa);
        wb16[i] = __builtin_bit_cast(unsigned, pb);
    }
}

// ---------------------------------------------------------------------------
// GRU scan (r17). r16 structure (1 wave/chain, 32x64, f16 weight pairs,
// 1 readlane per h-pair) with the MAC engine fixed: r16 used
// __builtin_amdgcn_fdot2, which gfx950 LOWERS to cvt+2xfma (no native
// v_dot2_f32_f16 on CDNA4) -> ~400 VALU insts/step, issue-bound at 74% of
// one SIMD (VALUBusy 2.3% = 74% of 1/4-CU ceiling; 1067 cyc/step). CDNA4
// DOES have v_pk_fma_f16 (VOP3P): __hfma2 = 2 MACs/inst. 96 hfma2 + 32
// readlane + ~70 misc ~ 200 insts ~ 540 cyc/step expected.
// Accuracy: products+accum in f16, 4 sub-accumulators/gate so each partial
// sum holds <=16 products (|sum|<=2, f16 ulp ~1e-3) -> dot err ~1e-2,
// absmax ~0.03-0.08 vs 0.24 threshold. hcur & gate math stay fp32.
// ---------------------------------------------------------------------------
__global__ __launch_bounds__(64, 1)
__attribute__((amdgpu_waves_per_eu(1, 1)))
void gru_kernel(
    const float* __restrict__ xpa, const float* __restrict__ xpb,
    const unsigned* __restrict__ wa16, const unsigned* __restrict__ wb16,
    const float* __restrict__ bhh_a, const float* __restrict__ bhh_b,
    float* __restrict__ hs_a, float* __restrict__ hs_b)
{
    const int blk = blockIdx.x;      // 0..31
    const int b = blk >> 1;
    const int which = blk & 1;
    const float* xp    = which ? xpb  : xpa;
    const unsigned* wf = which ? wb16 : wa16;
    const float* bhh   = which ? bhh_b : bhh_a;
    float* hs          = which ? hs_b  : hs_a;

    const int j = threadIdx.x;       // 0..63

    const uint4* pr = (const uint4*)(wf + (size_t)j * 32);
    const uint4* pz = (const uint4*)(wf + (size_t)(j + 64) * 32);
    const uint4* pn = (const uint4*)(wf + (size_t)(j + 128) * 32);
    uint4 r0 = pr[0], r1 = pr[1], r2 = pr[2], r3 = pr[3];
    uint4 r4 = pr[4], r5 = pr[5], r6 = pr[6], r7 = pr[7];
    uint4 z0 = pz[0], z1 = pz[1], z2 = pz[2], z3 = pz[3];
    uint4 z4 = pz[4], z5 = pz[5], z6 = pz[6], z7 = pz[7];
    uint4 n0 = pn[0], n1 = pn[1], n2 = pn[2], n3 = pn[3];
    uint4 n4 = pn[4], n5 = pn[5], n6 = pn[6], n7 = pn[7];

    const float br = bhh[j], bz = bhh[j + 64], bn = bhh[j + 128];

    const float* xrow = xp + (size_t)b * SS * GG;
    float* hrow = hs + (size_t)b * SS * HH;
    float hcur = 0.f;

    float xr = xrow[j], xz = xrow[j + 64], xn = xrow[j + 128];

#define BCH2(u) __builtin_bit_cast(__half2, (unsigned)(u))
#define RLH(k) ((unsigned)__builtin_amdgcn_readlane(__builtin_bit_cast(int, hp), (k)))
#define QUAD(q)                                                               \
    {                                                                         \
        unsigned u0_ = RLH(8*(q) + 0), u1_ = RLH(8*(q) + 2);                  \
        unsigned u2_ = RLH(8*(q) + 4), u3_ = RLH(8*(q) + 6);                  \
        __half2 h0_ = BCH2(u0_), h1_ = BCH2(u1_);                             \
        __half2 h2_ = BCH2(u2_), h3_ = BCH2(u3_);                             \
        cr0 = __hfma2(BCH2(r##q.x), h0_, cr0);                                \
        cr1 = __hfma2(BCH2(r##q.y), h1_, cr1);                                \
        cr2 = __hfma2(BCH2(r##q.z), h2_, cr2);                                \
        cr3 = __hfma2(BCH2(r##q.w), h3_, cr3);                                \
        cz0 = __hfma2(BCH2(z##q.x), h0_, cz0);                                \
        cz1 = __hfma2(BCH2(z##q.y), h1_, cz1);                                \
        cz2 = __hfma2(BCH2(z##q.z), h2_, cz2);                                \
        cz3 = __hfma2(BCH2(z##q.w), h3_, cz3);                                \
        cn0 = __hfma2(BCH2(n##q.x), h0_, cn0);                                \
        cn1 = __hfma2(BCH2(n##q.y), h1_, cn1);                                \
        cn2 = __hfma2(BCH2(n##q.z), h2_, cn2);                                \
        cn3 = __hfma2(BCH2(n##q.w), h3_, cn3);                                \
    }

    for (int s = 0; s < SS; ++s) {
        // Prefetch next step's xp (last iter over-reads into the adjacent
        // workspace region — harmless, value discarded).
        const float* nx = xrow + GG;
        float nxr = nx[j], nxz = nx[j + 64], nxn = nx[128 + j];

        // pack (h[2k], h[2k+1]) into every lane of the pair
        float partner = __shfl_xor(hcur, 1);
        float ev = (j & 1) ? partner : hcur;
        float od = (j & 1) ? hcur : partner;
        f16x2 hp = __builtin_amdgcn_cvt_pkrtz(ev, od);

        __half2 zh = __float2half2_rn(0.f);
        __half2 cr0 = zh, cr1 = zh, cr2 = zh, cr3 = zh;
        __half2 cz0 = zh, cz1 = zh, cz2 = zh, cz3 = zh;
        __half2 cn0 = zh, cn1 = zh, cn2 = zh, cn3 = zh;
        QUAD(0) QUAD(1) QUAD(2) QUAD(3)
        QUAD(4) QUAD(5) QUAD(6) QUAD(7)

        float2 fr0 = __half22float2(cr0), fr1 = __half22float2(cr1);
        float2 fr2 = __half22float2(cr2), fr3 = __half22float2(cr3);
        float2 fz0 = __half22float2(cz0), fz1 = __half22float2(cz1);
        float2 fz2 = __half22float2(cz2), fz3 = __half22float2(cz3);
        float2 fn0 = __half22float2(cn0), fn1 = __half22float2(cn1);
        float2 fn2 = __half22float2(cn2), fn3 = __half22float2(cn3);
        float arr = br + ((fr0.x + fr0.y) + (fr1.x + fr1.y))
                       + ((fr2.x + fr2.y) + (fr3.x + fr3.y));
        float azz = bz + ((fz0.x + fz0.y) + (fz1.x + fz1.y))
                       + ((fz2.x + fz2.y) + (fz3.x + fz3.y));
        float ann = bn + ((fn0.x + fn0.y) + (fn1.x + fn1.y))
                       + ((fn2.x + fn2.y) + (fn3.x + fn3.y));

        float r = sigmoid_f(xr + arr);
        float z = sigmoid_f(xz + azz);
        float n = tanh_f(xn + r * ann);
        hcur = fmaf(z, hcur - n, n);
        hrow[j] = hcur;

        xr = nxr; xz = nxz; xn = nxn;
        xrow += GG;
        hrow += HH;
    }
#undef QUAD
#undef RLH
#undef BCH2
}

// ---------------------------------------------------------------------------
// FUSED attn_val + scanA. One block per (batch, 16-row tile).
// ---------------------------------------------------------------------------
__global__ __launch_bounds__(128) void attn_scanA_kernel(
    const float* __restrict__ h_alpha, const float* __restrict__ h_beta,
    const float* __restrict__ emb, const float* __restrict__ M,
    const float* __restrict__ Wa, const float* __restrict__ ba,
    const float* __restrict__ Wb, const float* __restrict__ bb,
    float* __restrict__ val, float* __restrict__ wj,
    float* __restrict__ tsum, float* __restrict__ wsum)
{
    const int b = blockIdx.x, tt = blockIdx.y;
    const int t = threadIdx.x;       // 0..127
    const int j0 = tt * 16;
    __shared__ float hb_s[HH];
    __shared__ float wj_s;

    const float bbt = bb[t];
    const float4* wrow = (const float4*)&Wb[(size_t)t * HH];

    float ts = 0.f;
    float ws = 0.f;

    for (int jj = 0; jj < 16; ++jj) {
        const int row = b * SS + j0 + jj;
        if (t < 64) {
            hb_s[t] = h_beta[(size_t)row * HH + t];
            float p = h_alpha[(size_t)row * HH + t] * Wa[t];
            #pragma unroll
            for (int off = 32; off > 0; off >>= 1) p += __shfl_down(p, off);
            if (t == 0) {
                float a = __expf(p + ba[0]) * M[row];
                wj_s = a;
                wj[row] = a;
            }
        }
        __syncthreads();

        float acc = bbt;
        #pragma unroll
        for (int k = 0; k < 16; ++k) {
            float4 w4 = wrow[k];
            float4 h4 = *(const float4*)&hb_s[k * 4];
            acc += w4.x*h4.x + w4.y*h4.y + w4.z*h4.z + w4.w*h4.w;
        }
        float v = tanh_f(acc) * emb[(size_t)row * EE + t] * wj_s;
        val[(size_t)row * EE + t] = v;
        ts += v;
        if (t == 0) ws += wj_s;
        __syncthreads();   // hb_s/wj_s reused next row
    }

    tsum[((size_t)(b * TT + tt)) * EE + t] = ts;
    if (t == 0) wsum[b * TT + tt] = ws;
}

// ---------------------------------------------------------------------------
// FUSED scanB + proj. One block per (batch, 16-row tile); wtd stays in LDS.
// ---------------------------------------------------------------------------
__global__ __launch_bounds__(128) void scanB_proj_kernel(
    const float* __restrict__ val, const float* __restrict__ wj,
    const float* __restrict__ tsum, const float* __restrict__ wsum,
    const float* __restrict__ Wp, const float* __restrict__ bp,
    const float* __restrict__ M, float* __restrict__ out)
{
    const int b = blockIdx.x, tt = blockIdx.y;
    const int t = threadIdx.x;       // 0..127  (= e for the scan phase)
    const int j0 = tt * 16;

    __shared__ float wtd_s[16][132];
    __shared__ float wp_s[8][132];

    // beyond-tile suffix
    float se = 0.f;
    for (int t2 = tt + 1; t2 < TT; ++t2)
        se += tsum[((size_t)(b * TT + t2)) * EE + t];
    float d = 1e-10f;
    for (int t2 = tt + 1; t2 < TT; ++t2)
        d += wsum[b * TT + t2];

    // in-tile suffix (16 steps), results stay in LDS
    for (int jj = 15; jj >= 0; --jj) {
        size_t idx = ((size_t)(b * SS + j0 + jj)) * EE + t;
        se += val[idx];
        d += wj[b * SS + j0 + jj];
        wtd_s[jj][t] = se / d;
    }

    // stage Wp (8 x 128): 256 float4 total, 2 per thread
    #pragma unroll
    for (int it = 0; it < 2; ++it) {
        int idx = t + it * 128;      // 0..255
        int r = idx >> 5;            // 0..7
        int c = idx & 31;            // 0..31
        *(float4*)&wp_s[r][c * 4] = *(const float4*)&Wp[(size_t)r * EE + c * 4];
    }
    __syncthreads();

    // projection: thread = (row r, output l)
    const int r = t >> 3, l = t & 7;
    float acc = 0.f;
    #pragma unroll
    for (int i = 0; i < 32; ++i) {
        float4 a = *(const float4*)&wtd_s[r][i * 4];
        float4 w = *(const float4*)&wp_s[l][i * 4];
        acc += a.x*w.x + a.y*w.y + a.z*w.z + a.w*w.w;
    }
    const int row = b * SS + j0 + r;
    out[(size_t)row * LL + l] = (acc + bp[l]) * M[row];
}

// ---------------------------------------------------------------------------
// cur_output[b,l] = sum_s all_output[b,s,l] * cur_M[b,s]
// ---------------------------------------------------------------------------
__global__ __launch_bounds__(256) void cur_kernel(
    const float* __restrict__ out_all, const float* __restrict__ curM,
    float* __restrict__ out_cur)
{
    const int b = blockIdx.x;
    const int t = threadIdx.x;
    const int l = t & 7, c = t >> 3;
    float p = 0.f;
    #pragma unroll
    for (int k = 0; k < 8; ++k) {
        int s = c + k * 32;
        p += out_all[((size_t)(b * SS + s)) * LL + l] * curM[b * SS + s];
    }
    __shared__ float red[32][9];
    red[c][l] = p;
    __syncthreads();
    if (t < 8) {
        float sum = 0.f;
        for (int c2 = 0; c2 < 32; ++c2) sum += red[c2][t];
        out_cur[b * LL + t] = sum;
    }
}

// ---------------------------------------------------------------------------
extern "C" void kernel_launch(void* const* d_in, const int* in_sizes, int n_in,
                              void* d_out, int out_size, void* d_ws, size_t ws_size,
                              hipStream_t stream)
{
    const float* X       = (const float*)d_in[0];
    const float* M       = (const float*)d_in[1];
    const float* cur_M   = (const float*)d_in[2];
    const float* W_embed = (const float*)d_in[3];
    const float* b_embed = (const float*)d_in[4];
    const float* Wih_a   = (const float*)d_in[5];
    const float* Whh_a   = (const float*)d_in[6];
    const float* bih_a   = (const float*)d_in[7];
    const float* bhh_a   = (const float*)d_in[8];
    const float* Wih_b   = (const float*)d_in[9];
    const float* Whh_b   = (const float*)d_in[10];
    const float* bih_b   = (const float*)d_in[11];
    const float* bhh_b   = (const float*)d_in[12];
    const float* Wb      = (const float*)d_in[13];
    const float* bb      = (const float*)d_in[14];
    const float* Wa      = (const float*)d_in[15];
    const float* ba      = (const float*)d_in[16];
    const float* Wp      = (const float*)d_in[17];
    const float* bp      = (const float*)d_in[18];
    float* out = (float*)d_out;

    float* ws  = (float*)d_ws;
    float* emb = ws;                          // B*S*E
    float* xpa = emb + (size_t)BB*SS*EE;      // B*S*192
    float* xpb = xpa + (size_t)BB*SS*GG;
    float* ha  = xpb + (size_t)BB*SS*GG;      // B*S*H
    float* hb  = ha  + (size_t)BB*SS*HH;
    float* val = hb  + (size_t)BB*SS*HH;      // B*S*E
    float* wjv = val + (size_t)BB*SS*EE;      // B*S
    float* tsum = wjv + (size_t)BB*SS;        // B*TT*E
    float* wsum = tsum + (size_t)BB*TT*EE;    // B*TT
    unsigned* wa16 = (unsigned*)(wsum + (size_t)BB*TT);  // 6144 u32
    unsigned* wb16 = wa16 + (size_t)GG*HH/2;             // 6144 u32

    const int ROWS = BB * SS;                 // 4096

    cvt_w16_kernel<<<24, 256, 0, stream>>>(Whh_a, Whh_b, wa16, wb16);
    gemm_bt<<<dim3(ROWS/32, EE/64), 256, 0, stream>>>(X, W_embed, b_embed, emb, EE, FF);
    gemm_bt_dual<<<dim3(ROWS/32, (GG+63)/64, 2), 256, 0, stream>>>(
        emb, Wih_a, bih_a, xpa, Wih_b, bih_b, xpb, GG, EE);
    gru_kernel<<<32, 64, 0, stream>>>(xpa, xpb, wa16, wb16, bhh_a, bhh_b, ha, hb);
    attn_scanA_kernel<<<dim3(BB, TT), 128, 0, stream>>>(
        ha, hb, emb, M, Wa, ba, Wb, bb, val, wjv, tsum, wsum);
    scanB_proj_kernel<<<dim3(BB, TT), 128, 0, stream>>>(
        val, wjv, tsum, wsum, Wp, bp, M, out);
    cur_kernel<<<BB, 256, 0, stream>>>(out, cur_M, out + (size_t)BB*SS*LL);
}